// Round 9
// baseline (242.153 us; speedup 1.0000x reference)
//
#include <hip/hip_runtime.h>

#define NCH 5  // thermostat chain length (C) — fixed by the problem

// native vector type for nontemporal builtin (HIP float4 class is rejected)
typedef float f32x4 __attribute__((ext_vector_type(4)));

// ---------------------------------------------------------------------------
// Two-kernel structure, round-9 refinement of the 165.5-us round-8 version:
// the per-block chain prelude is hoisted OUT of K2 into K1's tail.
//
// K1 (nhc_reduce_chain): block (b, slice) reduces its 2048-atom slice and
//   publishes the partial as (bits, ~bits) [self-validating: poison fill can
//   never satisfy v == ~v; replay-stale bits are identical since inputs are
//   restored; validation also defeats load-load reordering, so the poll can
//   be fully RELAXED]. Blocks with slice==0 (linear ids 0..31, dispatched
//   FIRST) then poll their batch's 64 partials -- bounded 4096 iters with
//   self-service fallback (recompute from read-only inputs) -> hang-proof;
//   protocol identical to the one that passed in r3/r7, but only 32 polling
//   waves here, overlapped with K1's own streaming tail. Lane 0 runs the
//   14-substep SY chain and writes scale[b] + pos_nhc/mom_nhc.
// K2 (nhc_scale): pure stream -- s = scale[b] (stream-ordered after K1, no
//   protocol), 6 preloads, scale, nontemporal store. No LDS, no barrier,
//   no divergence: removes ~2 us of per-block prelude from K2's makespan.
//
// Retained from r8: XCD-aligned batch-minor grids (blockIdx.x = batch ->
// batch b pinned to XCD b%8 in both kernels), lane-contiguous loads,
// NT stores, __expf chain (args O(1e-3), abs err ~1e-7 << threshold).
// ---------------------------------------------------------------------------

__global__ __launch_bounds__(256) void nhc_reduce_chain(
    const float* __restrict__ mom, const float* __restrict__ mas,
    const float* __restrict__ kbt, const float* __restrict__ dtm,
    const float* __restrict__ pos_nhc, const float* __restrict__ mom_nhc,
    const float* __restrict__ mas_nhc, const float* __restrict__ stp,
    float* __restrict__ out_posnhc, float* __restrict__ out_momnhc,
    unsigned int* __restrict__ sig_part, unsigned int* __restrict__ sig_chk,
    float* __restrict__ scale, int n_atoms, int nd, float dof)
{
    const int b     = blockIdx.x;          // batch  (x-minor -> fixed XCD)
    const int slice = blockIdx.y;          // 0..63
    const int tid   = threadIdx.x;
    const float* momb = mom + (size_t)b * nd;
    const float* masb = mas + (size_t)b * n_atoms;

    // ---- phase A: KE partial over this block's 2048 atoms, coalesced ----
    float ke = 0.0f;
    {
        const int base = slice * 2048;
        #pragma unroll
        for (int r = 0; r < 8; ++r) {
            const int a = base + r * 256 + tid;
            const float3 p = *(const float3*)(momb + 3 * (size_t)a);
            const float  m = masb[a];
            ke += (p.x * p.x + p.y * p.y + p.z * p.z) / m;
        }
    }

    // deterministic block reduce: fixed butterfly + fixed wave order
    #pragma unroll
    for (int off = 32; off > 0; off >>= 1) ke += __shfl_down(ke, off, 64);
    __shared__ float lds[4];
    const int lane = tid & 63, wv = tid >> 6;
    if (lane == 0) lds[wv] = ke;
    __syncthreads();
    if (tid == 0) {
        const float pblk = lds[0] + lds[1] + lds[2] + lds[3];
        const unsigned int pb = __float_as_uint(pblk);
        const int i = b * 64 + slice;
        __hip_atomic_store(&sig_part[i], pb, __ATOMIC_RELAXED,
                           __HIP_MEMORY_SCOPE_AGENT);
        __hip_atomic_store(&sig_chk[i], ~pb, __ATOMIC_RELEASE,
                           __HIP_MEMORY_SCOPE_AGENT);
    }

    if (slice != 0) return;

    // ---- slice-0 block: gather 64 partials (bounded poll), run chain ----
    if (tid < 64) {
        const int j = tid;                 // which slice's partial
        const int i = b * 64 + j;
        unsigned int pb = 0u;
        bool got = false;
        for (int it = 0; it < 4096; ++it) {   // bounded; no hang possible
            const unsigned int ck =
                __hip_atomic_load(&sig_chk[i], __ATOMIC_RELAXED,
                                  __HIP_MEMORY_SCOPE_AGENT);
            pb = __hip_atomic_load(&sig_part[i], __ATOMIC_RELAXED,
                                   __HIP_MEMORY_SCOPE_AGENT);
            if (ck == ~pb) { got = true; break; }   // self-validating
            __builtin_amdgcn_s_sleep(2);
        }
        float t;
        if (got) {
            t = __uint_as_float(pb);
        } else {
            // self-service fallback: recompute slice j from read-only
            // inputs (bounded, scheduling-independent; ulp-level order
            // difference is far below the output tolerance).
            float acc = 0.0f;
            const int base = j * 2048;
            for (int a = base; a < base + 2048; ++a) {
                const float3 p = *(const float3*)(momb + 3 * (size_t)a);
                acc += (p.x * p.x + p.y * p.y + p.z * p.z) / masb[a];
            }
            t = acc;
        }
        #pragma unroll
        for (int off = 32; off > 0; off >>= 1) t += __shfl_down(t, off, 64);

        if (tid == 0) {
            float kin = t;
            constexpr double W1 = 0.78451361047756;
            constexpr double W2 = 0.235573213359357;
            constexpr double W3 = -1.17767998417887;
            constexpr double W4 = 1.0 - 2.0 * (W1 + W2 + W3);
            const float syw[7] = {(float)W1, (float)W2, (float)W3, (float)W4,
                                  (float)W3, (float)W2, (float)W1};

            const float kb = kbt[b], dt = dtm[b], st = stp[0];
            float pnh[NCH], mnh[NCH], qn[NCH];
            #pragma unroll
            for (int c = 0; c < NCH; ++c) {
                pnh[c] = pos_nhc[b * NCH + c];
                mnh[c] = mom_nhc[b * NCH + c];
                qn[c]  = mas_nhc[b * NCH + c];
            }

            float Scum = 1.0f;
            for (int r = 0; r < 14; ++r) {        // NRESPA(2) x 7 SY weights
                const float w   = syw[r % 7];
                const float dea = dt * (st * w * 0.5f);
                const float de2 = dea * 0.5f;
                const float de4 = dea * 0.25f;

                float gg[NCH], mc[NCH];
                gg[0] = kin - kb * dof;
                #pragma unroll
                for (int j2 = 1; j2 < NCH; ++j2)
                    gg[j2] = mnh[j2 - 1] * mnh[j2 - 1] / qn[j2 - 1] - kb;
                #pragma unroll
                for (int c = 0; c < NCH; ++c) mc[c] = mnh[c];

                // first half-kick + chain pass (pre-step g)
                mc[NCH - 1] += gg[NCH - 1] * de2;
                #pragma unroll
                for (int j2 = NCH - 2; j2 >= 0; --j2) {
                    const float f = __expf(-mc[j2 + 1] / qn[j2 + 1] * de4);
                    mc[j2] = (mc[j2] * f + gg[j2] * de2) * f;
                }

                // drift + momentum rescale (carried algebraically on kin)
                #pragma unroll
                for (int c = 0; c < NCH; ++c) pnh[c] += mc[c] / qn[c] * dea;
                const float s = __expf(-mc[0] / qn[0] * dea);
                Scum *= s;
                kin  *= s * s;   // sum((s*mom)^2/mas) == s^2 * KE

                // second half: g0 from rescaled KE; g[1..] unchanged
                gg[0] = kin - kb * dof;
                #pragma unroll
                for (int j2 = NCH - 2; j2 >= 0; --j2) {
                    const float f = __expf(-mc[j2 + 1] / qn[j2 + 1] * de4);
                    mc[j2] = (mc[j2] * f + gg[j2] * de2) * f;
                }
                mc[NCH - 1] += gg[NCH - 1] * de2;

                #pragma unroll
                for (int c = 0; c < NCH; ++c) mnh[c] = mc[c];
            }

            scale[b] = Scum;
            #pragma unroll
            for (int c = 0; c < NCH; ++c) {
                out_posnhc[b * NCH + c] = pnh[c];
                out_momnhc[b * NCH + c] = mnh[c];
            }
        }
    }
}

// K2: pure streaming scale. No LDS, no barrier, no divergence.
__global__ __launch_bounds__(256) void nhc_scale(
    const float* __restrict__ mom, const float* __restrict__ scale,
    float* __restrict__ out_mom, int n4_per_batch)
{
    const int b   = blockIdx.x;            // batch (x-minor -> fixed XCD)
    const int x   = blockIdx.y;            // 0..63 slice
    const int tid = threadIdx.x;

    const f32x4* in4 = (const f32x4*)mom + (size_t)b * n4_per_batch
                     + (size_t)x * 1536;   // 2048 atoms = 1536 float4
    f32x4*       o4  = (f32x4*)out_mom   + (size_t)b * n4_per_batch
                     + (size_t)x * 1536;

    // scale load issues in parallel with the 6 data loads (independent)
    const float s = scale[b];
    f32x4 v0 = in4[0 * 256 + tid];
    f32x4 v1 = in4[1 * 256 + tid];
    f32x4 v2 = in4[2 * 256 + tid];
    f32x4 v3 = in4[3 * 256 + tid];
    f32x4 v4 = in4[4 * 256 + tid];
    f32x4 v5 = in4[5 * 256 + tid];

    v0 *= s; __builtin_nontemporal_store(v0, &o4[0 * 256 + tid]);
    v1 *= s; __builtin_nontemporal_store(v1, &o4[1 * 256 + tid]);
    v2 *= s; __builtin_nontemporal_store(v2, &o4[2 * 256 + tid]);
    v3 *= s; __builtin_nontemporal_store(v3, &o4[3 * 256 + tid]);
    v4 *= s; __builtin_nontemporal_store(v4, &o4[4 * 256 + tid]);
    v5 *= s; __builtin_nontemporal_store(v5, &o4[5 * 256 + tid]);
}

extern "C" void kernel_launch(void* const* d_in, const int* in_sizes, int n_in,
                              void* d_out, int out_size, void* d_ws, size_t ws_size,
                              hipStream_t stream) {
    // input order: pos(0, unused), mom(1), mas(2), kbt(3), dtm(4),
    //              pos_nhc(5), mom_nhc(6), mas_nhc(7), stp(8)
    const float* mom     = (const float*)d_in[1];
    const float* mas     = (const float*)d_in[2];
    const float* kbt     = (const float*)d_in[3];
    const float* dtm     = (const float*)d_in[4];
    const float* pos_nhc = (const float*)d_in[5];
    const float* mom_nhc = (const float*)d_in[6];
    const float* mas_nhc = (const float*)d_in[7];
    const float* stp     = (const float*)d_in[8];

    const int B  = in_sizes[3];            // 32
    const int ND = in_sizes[1] / B;        // N*D = 393216
    const int N  = in_sizes[2] / B;        // 131072 atoms
    (void)n_in; (void)ws_size; (void)out_size;
    const float dof = (float)ND;

    unsigned int* sig_part = (unsigned int*)d_ws;          // B*64 u32
    unsigned int* sig_chk  = sig_part + (size_t)B * 64;    // B*64 u32
    float*        scale    = (float*)(sig_chk + (size_t)B * 64);  // B floats

    float* out_f      = (float*)d_out;
    float* out_posnhc = out_f + (size_t)B * ND;
    float* out_momnhc = out_posnhc + (size_t)B * NCH;

    // Batch-minor grids: blockIdx.x = batch -> XCD affinity b%8 in both
    // kernels; slice-0 blocks (ids 0..31) of K1 are dispatched first and
    // absorb the chain work in K1's tail.
    nhc_reduce_chain<<<dim3(B, N / 2048), 256, 0, stream>>>(
        mom, mas, kbt, dtm, pos_nhc, mom_nhc, mas_nhc, stp,
        out_posnhc, out_momnhc, sig_part, sig_chk, scale, N, ND, dof);

    const int n4 = ND / 4;                 // 98304 float4 per batch
    nhc_scale<<<dim3(B, 64), 256, 0, stream>>>(
        mom, scale, out_f, n4);
}

// Round 10
// 168.944 us; speedup vs baseline: 1.4333x; 1.4333x over previous
//
#include <hip/hip_runtime.h>

#define NCH 5  // thermostat chain length (C) — fixed by the problem

// native vector type for nontemporal builtins (HIP float4 class is rejected)
typedef float f32x4 __attribute__((ext_vector_type(4)));

// ---------------------------------------------------------------------------
// THREE-kernel structure. Lessons enforced (r1-r9):
//  * NO device-side spin/poll sync anywhere: every kernel with an
//    agent-scope poll measured 100-130 us regardless of who polls (r3/r7/r9)
//    or hung (r2). Kernel boundaries are the only cheap sync here.
//  * r8's two-kernel version (165.5 us) paid a redundant ~3-4 us wave-0
//    prelude (64-partial reduce + lane-serial 126-exp chain) in EVERY one of
//    K2's 2048 blocks before any store could issue. That prelude now runs
//    once per batch in a tiny middle kernel.
//
// K1 nhc_reduce  : per-(batch,slice) KE partial, lane-contiguous float3+f32
//                  loads, deterministic butterfly+LDS reduce -> partials[].
//                  (verbatim the r8 kernel that benched 165.5)
// K1.5 nhc_chain : 32 blocks x 64 thr; reduce the 64 partials, lane 0 runs
//                  the 14-substep SY chain, writes scale[b] + pos_nhc +
//                  mom_nhc. ~2 us including launch.
// K2 nhc_scale   : pure stream: s = scale[b]; 6x NT-load, scale, NT-store.
//                  No LDS, no __syncthreads, no divergence.
//
// Retained r8 layout decisions: batch-minor grids (blockIdx.x = batch) pin
// batch b to XCD b%8 in all kernels (partial L2 reuse of mom between K1 and
// K2); K1 loads stay CACHED (so mom is L3/L2-resident for K2's re-read);
// out_mom stores are nontemporal (never re-read); __expf in the chain
// (args O(1e-3), abs err ~1e-7, three orders below the 13.68 threshold).
// ---------------------------------------------------------------------------

__global__ __launch_bounds__(256) void nhc_reduce(
    const float* __restrict__ mom, const float* __restrict__ mas,
    float* __restrict__ partials, int n_atoms, int nd)
{
    const int b     = blockIdx.x;          // batch  (x-minor -> fixed XCD)
    const int slice = blockIdx.y;          // 0..63
    const float* momb = mom + (size_t)b * nd;
    const float* masb = mas + (size_t)b * n_atoms;

    float ke = 0.0f;
    const int base = slice * 2048;
    #pragma unroll
    for (int r = 0; r < 8; ++r) {
        const int a = base + r * 256 + threadIdx.x;
        const float3 p = *(const float3*)(momb + 3 * (size_t)a);
        const float  m = masb[a];
        ke += (p.x * p.x + p.y * p.y + p.z * p.z) / m;
    }

    // deterministic block reduce: fixed butterfly + fixed wave order
    #pragma unroll
    for (int off = 32; off > 0; off >>= 1) ke += __shfl_down(ke, off, 64);
    __shared__ float lds[4];
    const int lane = threadIdx.x & 63, wv = threadIdx.x >> 6;
    if (lane == 0) lds[wv] = ke;
    __syncthreads();
    if (threadIdx.x == 0)
        partials[(size_t)b * 64 + slice] = lds[0] + lds[1] + lds[2] + lds[3];
}

// K1.5: one 64-thread block per batch; partials reduce + SY chain.
__global__ __launch_bounds__(64) void nhc_chain(
    const float* __restrict__ partials,
    const float* __restrict__ kbt, const float* __restrict__ dtm,
    const float* __restrict__ pos_nhc, const float* __restrict__ mom_nhc,
    const float* __restrict__ mas_nhc, const float* __restrict__ stp,
    float* __restrict__ scale, float* __restrict__ out_posnhc,
    float* __restrict__ out_momnhc, float dof)
{
    const int b   = blockIdx.x;
    const int tid = threadIdx.x;           // 0..63

    float t = partials[(size_t)b * 64 + tid];
    #pragma unroll
    for (int off = 32; off > 0; off >>= 1) t += __shfl_down(t, off, 64);

    if (tid != 0) return;

    float kin = t;
    constexpr double W1 = 0.78451361047756;
    constexpr double W2 = 0.235573213359357;
    constexpr double W3 = -1.17767998417887;
    constexpr double W4 = 1.0 - 2.0 * (W1 + W2 + W3);
    const float syw[7] = {(float)W1, (float)W2, (float)W3, (float)W4,
                          (float)W3, (float)W2, (float)W1};

    const float kb = kbt[b], dt = dtm[b], st = stp[0];
    float pnh[NCH], mnh[NCH], qn[NCH];
    #pragma unroll
    for (int c = 0; c < NCH; ++c) {
        pnh[c] = pos_nhc[b * NCH + c];
        mnh[c] = mom_nhc[b * NCH + c];
        qn[c]  = mas_nhc[b * NCH + c];
    }

    float Scum = 1.0f;
    for (int r = 0; r < 14; ++r) {        // NRESPA(2) x 7 SY weights
        const float w   = syw[r % 7];
        const float dea = dt * (st * w * 0.5f);
        const float de2 = dea * 0.5f;
        const float de4 = dea * 0.25f;

        float gg[NCH], mc[NCH];
        gg[0] = kin - kb * dof;
        #pragma unroll
        for (int j = 1; j < NCH; ++j)
            gg[j] = mnh[j - 1] * mnh[j - 1] / qn[j - 1] - kb;
        #pragma unroll
        for (int c = 0; c < NCH; ++c) mc[c] = mnh[c];

        // first half-kick + chain pass (pre-step g)
        mc[NCH - 1] += gg[NCH - 1] * de2;
        #pragma unroll
        for (int j = NCH - 2; j >= 0; --j) {
            const float f = __expf(-mc[j + 1] / qn[j + 1] * de4);
            mc[j] = (mc[j] * f + gg[j] * de2) * f;
        }

        // drift + momentum rescale (carried algebraically on kin)
        #pragma unroll
        for (int c = 0; c < NCH; ++c) pnh[c] += mc[c] / qn[c] * dea;
        const float s = __expf(-mc[0] / qn[0] * dea);
        Scum *= s;
        kin  *= s * s;   // sum((s*mom)^2/mas) == s^2 * KE

        // second half: g0 from rescaled KE; g[1..] unchanged
        gg[0] = kin - kb * dof;
        #pragma unroll
        for (int j = NCH - 2; j >= 0; --j) {
            const float f = __expf(-mc[j + 1] / qn[j + 1] * de4);
            mc[j] = (mc[j] * f + gg[j] * de2) * f;
        }
        mc[NCH - 1] += gg[NCH - 1] * de2;

        #pragma unroll
        for (int c = 0; c < NCH; ++c) mnh[c] = mc[c];
    }

    scale[b] = Scum;
    #pragma unroll
    for (int c = 0; c < NCH; ++c) {
        out_posnhc[b * NCH + c] = pnh[c];
        out_momnhc[b * NCH + c] = mnh[c];
    }
}

// K2: pure streaming scale. No LDS, no barrier, no divergence.
__global__ __launch_bounds__(256) void nhc_scale(
    const float* __restrict__ mom, const float* __restrict__ scale,
    float* __restrict__ out_mom, int n4_per_batch)
{
    const int b   = blockIdx.x;            // batch (x-minor -> fixed XCD)
    const int x   = blockIdx.y;            // 0..63 slice
    const int tid = threadIdx.x;

    const f32x4* in4 = (const f32x4*)mom + (size_t)b * n4_per_batch
                     + (size_t)x * 1536;   // 2048 atoms = 1536 float4
    f32x4*       o4  = (f32x4*)out_mom   + (size_t)b * n4_per_batch
                     + (size_t)x * 1536;

    const float s = scale[b];
    f32x4 v0 = __builtin_nontemporal_load(&in4[0 * 256 + tid]);
    f32x4 v1 = __builtin_nontemporal_load(&in4[1 * 256 + tid]);
    f32x4 v2 = __builtin_nontemporal_load(&in4[2 * 256 + tid]);
    f32x4 v3 = __builtin_nontemporal_load(&in4[3 * 256 + tid]);
    f32x4 v4 = __builtin_nontemporal_load(&in4[4 * 256 + tid]);
    f32x4 v5 = __builtin_nontemporal_load(&in4[5 * 256 + tid]);

    v0 *= s; __builtin_nontemporal_store(v0, &o4[0 * 256 + tid]);
    v1 *= s; __builtin_nontemporal_store(v1, &o4[1 * 256 + tid]);
    v2 *= s; __builtin_nontemporal_store(v2, &o4[2 * 256 + tid]);
    v3 *= s; __builtin_nontemporal_store(v3, &o4[3 * 256 + tid]);
    v4 *= s; __builtin_nontemporal_store(v4, &o4[4 * 256 + tid]);
    v5 *= s; __builtin_nontemporal_store(v5, &o4[5 * 256 + tid]);
}

extern "C" void kernel_launch(void* const* d_in, const int* in_sizes, int n_in,
                              void* d_out, int out_size, void* d_ws, size_t ws_size,
                              hipStream_t stream) {
    // input order: pos(0, unused), mom(1), mas(2), kbt(3), dtm(4),
    //              pos_nhc(5), mom_nhc(6), mas_nhc(7), stp(8)
    const float* mom     = (const float*)d_in[1];
    const float* mas     = (const float*)d_in[2];
    const float* kbt     = (const float*)d_in[3];
    const float* dtm     = (const float*)d_in[4];
    const float* pos_nhc = (const float*)d_in[5];
    const float* mom_nhc = (const float*)d_in[6];
    const float* mas_nhc = (const float*)d_in[7];
    const float* stp     = (const float*)d_in[8];

    const int B  = in_sizes[3];            // 32
    const int ND = in_sizes[1] / B;        // N*D = 393216
    const int N  = in_sizes[2] / B;        // 131072 atoms
    (void)n_in; (void)ws_size; (void)out_size;
    const float dof = (float)ND;

    float* partials = (float*)d_ws;                        // B*64 floats
    float* scale    = partials + (size_t)B * 64;           // B floats

    float* out_f      = (float*)d_out;
    float* out_posnhc = out_f + (size_t)B * ND;
    float* out_momnhc = out_posnhc + (size_t)B * NCH;

    // Batch-minor grids: blockIdx.x = batch -> XCD affinity b%8 everywhere.
    nhc_reduce<<<dim3(B, N / 2048), 256, 0, stream>>>(
        mom, mas, partials, N, ND);

    nhc_chain<<<dim3(B), 64, 0, stream>>>(
        partials, kbt, dtm, pos_nhc, mom_nhc, mas_nhc, stp,
        scale, out_posnhc, out_momnhc, dof);

    const int n4 = ND / 4;                 // 98304 float4 per batch
    nhc_scale<<<dim3(B, 64), 256, 0, stream>>>(
        mom, scale, out_f, n4);
}

// Round 11
// 165.597 us; speedup vs baseline: 1.4623x; 1.0202x over previous
//
#include <hip/hip_runtime.h>

#define NCH 5  // thermostat chain length (C) — fixed by the problem

// native vector type for nontemporal builtin (HIP float4 class is rejected)
typedef float f32x4 __attribute__((ext_vector_type(4)));

// ---------------------------------------------------------------------------
// FINAL: verbatim revert to the round-8 kernel — best verified at 165.5 us.
//
// Session conclusions baked into this structure (r0-r10):
//  * Cooperative launch is silently dropped by the harness (r1).
//  * Device-side spin/poll sync costs 100-130 us regardless of who polls
//    (r3/r7/r9) or hangs outright (r2) — kernel boundary is the only sync.
//  * Splitting the chain into a 3rd kernel regresses: the per-block chain
//    prelude is FREE in K2 (hidden under the preloads' latency), while the
//    extra launch + NT-load L2 bypass cost +3.4 us (r10).
//  * XCD-aligned batch-minor grids (blockIdx.x = batch -> batch b pinned to
//    XCD b%8 in both kernels) give K2 partial L2 reuse of mom (r8: -12 us).
//  * NT stores for out_mom (never re-read); CACHED loads everywhere else.
//  * __expf in the chain: args O(1e-3), abs err ~1e-7 << 13.68 threshold.
//
// K1 nhc_reduce: block (b, slice) reduces its 2048-atom slice of batch b.
//   Lane-contiguous loads: float3 mom (12 B lane stride) + scalar mas.
//   Deterministic butterfly + fixed-order LDS reduce -> partials[b*64+slice].
// K2 nhc_chain_scale: 6 float4 preloads issued FIRST (latency hides under
//   the prelude); wave 0 reduces the 64 partials and lane 0 runs the
//   14-substep SY chain redundantly per block (bit-identical); slice-0
//   block writes pos_nhc/mom_nhc; all blocks scale + NT-store their slice.
// ---------------------------------------------------------------------------

__global__ __launch_bounds__(256) void nhc_reduce(
    const float* __restrict__ mom, const float* __restrict__ mas,
    float* __restrict__ partials, int n_atoms, int nd)
{
    const int b     = blockIdx.x;          // batch  (x-minor -> fixed XCD)
    const int slice = blockIdx.y;          // 0..63
    const float* momb = mom + (size_t)b * nd;
    const float* masb = mas + (size_t)b * n_atoms;

    float ke = 0.0f;
    const int base = slice * 2048;
    #pragma unroll
    for (int r = 0; r < 8; ++r) {
        const int a = base + r * 256 + threadIdx.x;
        const float3 p = *(const float3*)(momb + 3 * (size_t)a);
        const float  m = masb[a];
        ke += (p.x * p.x + p.y * p.y + p.z * p.z) / m;
    }

    // deterministic block reduce: fixed butterfly + fixed wave order
    #pragma unroll
    for (int off = 32; off > 0; off >>= 1) ke += __shfl_down(ke, off, 64);
    __shared__ float lds[4];
    const int lane = threadIdx.x & 63, wv = threadIdx.x >> 6;
    if (lane == 0) lds[wv] = ke;
    __syncthreads();
    if (threadIdx.x == 0)
        partials[(size_t)b * 64 + slice] = lds[0] + lds[1] + lds[2] + lds[3];
}

// Kernel 2: fused chain + scale. Preload 6 float4 (block-local 24 KB slice)
// before the wave-0 chain prelude so load latency hides under it; __expf in
// the chain; NT stores.
__global__ __launch_bounds__(256) void nhc_chain_scale(
    const float* __restrict__ mom, const float* __restrict__ partials,
    const float* __restrict__ kbt, const float* __restrict__ dtm,
    const float* __restrict__ pos_nhc, const float* __restrict__ mom_nhc,
    const float* __restrict__ mas_nhc, const float* __restrict__ stp,
    float* __restrict__ out_mom, float* __restrict__ out_posnhc,
    float* __restrict__ out_momnhc,
    int n4_per_batch, float dof)
{
    const int b   = blockIdx.x;            // batch (x-minor -> fixed XCD)
    const int x   = blockIdx.y;            // 0..63 slice
    const int tid = threadIdx.x;

    const f32x4* in4 = (const f32x4*)mom + (size_t)b * n4_per_batch
                     + (size_t)x * 1536;   // 2048 atoms = 1536 float4
    f32x4*       o4  = (f32x4*)out_mom   + (size_t)b * n4_per_batch
                     + (size_t)x * 1536;

    // ---- issue data loads first (latency hides under the chain) ----
    f32x4 v0 = in4[0 * 256 + tid];
    f32x4 v1 = in4[1 * 256 + tid];
    f32x4 v2 = in4[2 * 256 + tid];
    f32x4 v3 = in4[3 * 256 + tid];
    f32x4 v4 = in4[4 * 256 + tid];
    f32x4 v5 = in4[5 * 256 + tid];

    __shared__ float s_scale;

    // ---- wave-0 prelude: partials reduce + redundant SY chain ----
    if (tid < 64) {
        float t = partials[(size_t)b * 64 + tid];
        #pragma unroll
        for (int off = 32; off > 0; off >>= 1) t += __shfl_down(t, off, 64);

        if (tid == 0) {
            float kin = t;
            constexpr double W1 = 0.78451361047756;
            constexpr double W2 = 0.235573213359357;
            constexpr double W3 = -1.17767998417887;
            constexpr double W4 = 1.0 - 2.0 * (W1 + W2 + W3);
            const float syw[7] = {(float)W1, (float)W2, (float)W3, (float)W4,
                                  (float)W3, (float)W2, (float)W1};

            const float kb = kbt[b], dt = dtm[b], st = stp[0];
            float pnh[NCH], mnh[NCH], qn[NCH];
            #pragma unroll
            for (int c = 0; c < NCH; ++c) {
                pnh[c] = pos_nhc[b * NCH + c];
                mnh[c] = mom_nhc[b * NCH + c];
                qn[c]  = mas_nhc[b * NCH + c];
            }

            float Scum = 1.0f;
            for (int r = 0; r < 14; ++r) {        // NRESPA(2) x 7 SY weights
                const float w   = syw[r % 7];
                const float dea = dt * (st * w * 0.5f);
                const float de2 = dea * 0.5f;
                const float de4 = dea * 0.25f;

                float gg[NCH], mc[NCH];
                gg[0] = kin - kb * dof;
                #pragma unroll
                for (int j = 1; j < NCH; ++j)
                    gg[j] = mnh[j - 1] * mnh[j - 1] / qn[j - 1] - kb;
                #pragma unroll
                for (int c = 0; c < NCH; ++c) mc[c] = mnh[c];

                // first half-kick + chain pass (pre-step g)
                mc[NCH - 1] += gg[NCH - 1] * de2;
                #pragma unroll
                for (int j = NCH - 2; j >= 0; --j) {
                    const float f = __expf(-mc[j + 1] / qn[j + 1] * de4);
                    mc[j] = (mc[j] * f + gg[j] * de2) * f;
                }

                // drift + momentum rescale (carried algebraically on kin)
                #pragma unroll
                for (int c = 0; c < NCH; ++c) pnh[c] += mc[c] / qn[c] * dea;
                const float s = __expf(-mc[0] / qn[0] * dea);
                Scum *= s;
                kin  *= s * s;   // sum((s*mom)^2/mas) == s^2 * KE

                // second half: g0 from rescaled KE; g[1..] unchanged
                gg[0] = kin - kb * dof;
                #pragma unroll
                for (int j = NCH - 2; j >= 0; --j) {
                    const float f = __expf(-mc[j + 1] / qn[j + 1] * de4);
                    mc[j] = (mc[j] * f + gg[j] * de2) * f;
                }
                mc[NCH - 1] += gg[NCH - 1] * de2;

                #pragma unroll
                for (int c = 0; c < NCH; ++c) mnh[c] = mc[c];
            }

            s_scale = Scum;
            if (x == 0) {
                #pragma unroll
                for (int c = 0; c < NCH; ++c) {
                    out_posnhc[b * NCH + c] = pnh[c];
                    out_momnhc[b * NCH + c] = mnh[c];
                }
            }
        }
    }
    __syncthreads();

    // ---- scale + nontemporal store ----
    const float s = s_scale;
    v0 *= s; __builtin_nontemporal_store(v0, &o4[0 * 256 + tid]);
    v1 *= s; __builtin_nontemporal_store(v1, &o4[1 * 256 + tid]);
    v2 *= s; __builtin_nontemporal_store(v2, &o4[2 * 256 + tid]);
    v3 *= s; __builtin_nontemporal_store(v3, &o4[3 * 256 + tid]);
    v4 *= s; __builtin_nontemporal_store(v4, &o4[4 * 256 + tid]);
    v5 *= s; __builtin_nontemporal_store(v5, &o4[5 * 256 + tid]);
}

extern "C" void kernel_launch(void* const* d_in, const int* in_sizes, int n_in,
                              void* d_out, int out_size, void* d_ws, size_t ws_size,
                              hipStream_t stream) {
    // input order: pos(0, unused), mom(1), mas(2), kbt(3), dtm(4),
    //              pos_nhc(5), mom_nhc(6), mas_nhc(7), stp(8)
    const float* mom     = (const float*)d_in[1];
    const float* mas     = (const float*)d_in[2];
    const float* kbt     = (const float*)d_in[3];
    const float* dtm     = (const float*)d_in[4];
    const float* pos_nhc = (const float*)d_in[5];
    const float* mom_nhc = (const float*)d_in[6];
    const float* mas_nhc = (const float*)d_in[7];
    const float* stp     = (const float*)d_in[8];

    const int B  = in_sizes[3];            // 32
    const int ND = in_sizes[1] / B;        // N*D = 393216
    const int N  = in_sizes[2] / B;        // 131072 atoms
    (void)n_in; (void)ws_size; (void)out_size;
    const float dof = (float)ND;

    float* partials = (float*)d_ws;        // B * 64 floats

    float* out_f      = (float*)d_out;
    float* out_posnhc = out_f + (size_t)B * ND;
    float* out_momnhc = out_posnhc + (size_t)B * NCH;

    // Batch-minor grids: blockIdx.x = batch so linear block id % 8 ==
    // batch % 8 in both kernels -> per-batch XCD affinity for L2 reuse.
    nhc_reduce<<<dim3(B, N / 2048), 256, 0, stream>>>(
        mom, mas, partials, N, ND);

    const int n4 = ND / 4;                 // 98304 float4 per batch
    nhc_chain_scale<<<dim3(B, 64), 256, 0, stream>>>(
        mom, partials, kbt, dtm, pos_nhc, mom_nhc, mas_nhc, stp,
        out_f, out_posnhc, out_momnhc, n4, dof);
}